// Round 9
// baseline (816.400 us; speedup 1.0000x reference)
//
#include <hip/hip_runtime.h>
#include <hip/hip_bf16.h>

#define Bb 4
#define Nn 4096
#define C1 320
#define C2 256
#define Hh 5
#define HD 64
#define Mm (Bb*Nn)   // 16384

using bf16 = __hip_bfloat16;
typedef __attribute__((ext_vector_type(8))) short  short8;   // 8 bf16 = one MFMA A/B frag
typedef __attribute__((ext_vector_type(4))) short  short4_;
typedef __attribute__((ext_vector_type(4))) float  f32x4;    // MFMA C/D frag

__device__ __forceinline__ short f2s(float f) {
    bf16 h = __float2bfloat16(f);
    short s;
    __builtin_memcpy(&s, &h, 2);
    return s;
}

__device__ __forceinline__ float fexp2(float x) {
#if __has_builtin(__builtin_amdgcn_exp2f)
    return __builtin_amdgcn_exp2f(x);
#else
    return exp2f(x);
#endif
}

// packed f32x2 -> bf16x2 conversion (v_cvt_pk path), 4 values -> short4
__device__ __forceinline__ short4_ pack4(float p0, float p1, float p2, float p3) {
    float2 u; u.x = p0; u.y = p1;
    float2 v; v.x = p2; v.y = p3;
    __hip_bfloat162 a = __float22bfloat162_rn(u);
    __hip_bfloat162 b = __float22bfloat162_rn(v);
    short4_ r;
    __builtin_memcpy(&r, &a, 4);
    short tmp[2];
    __builtin_memcpy(tmp, &b, 4);
    r[2] = tmp[0]; r[3] = tmp[1];
    return r;
}

// XOR-swizzled LDS tile addressing: 64-elem rows, 8 blocks of 8 bf16 (16B).
// physical elem offset of (row, logical block bb) = row*64 + (bb ^ (row&7))*8
__device__ __forceinline__ int swz(int row, int bb) {
    return row * 64 + ((bb ^ (row & 7)) << 3);
}

// ---------------- fp32 -> bf16 convert, all 8 tensors in one launch ----------------
struct CvtArgs {
    const float* s[8];
    bf16* d[8];
    int off[9];   // cumulative offsets, off[8] = total
};

__global__ void cvt_all(CvtArgs a) {
    int i = (blockIdx.x * blockDim.x + threadIdx.x) * 4;
    if (i >= a.off[8]) return;
    int seg = 0;
    #pragma unroll
    for (int k = 1; k < 8; ++k) seg += (i >= a.off[k]);
    int j = i - a.off[seg];
    float4 v = *(const float4*)(a.s[seg] + j);
    short4_ o = { f2s(v.x), f2s(v.y), f2s(v.z), f2s(v.w) };
    *(short4_*)(a.d[seg] + j) = o;
}

// ---------------- generic GEMM: C[M,n0..] = A[M,K] x W[Nout,K]^T ----------------
// mode 0: store bf16*oscale to O1[row*320+col]
// mode 1: col<320 -> O1 (K part, [M,320]); col>=320 -> O2 = V transposed [B,H,64,N]
// mode 2: fp32 out Of[row*640 + ooff + col] + bias[col]
__global__ __launch_bounds__(256) void gemm_bt(
    const bf16* __restrict__ A, const bf16* __restrict__ W,
    int K, int mode, float oscale,
    bf16* __restrict__ O1, bf16* __restrict__ O2,
    const float* __restrict__ bias, float* __restrict__ Of, int ooff)
{
    __shared__ bf16 la[64 * 64];
    __shared__ bf16 lw[64 * 64];
    const int m0 = blockIdx.x * 64, n0 = blockIdx.y * 64;
    const int t = threadIdx.x;
    const int wave = t >> 6, lane = t & 63, l16 = lane & 15, quad = lane >> 4;
    const int sr = t >> 3, sb = t & 7;

    f32x4 acc[4] = {{0.f,0.f,0.f,0.f},{0.f,0.f,0.f,0.f},{0.f,0.f,0.f,0.f},{0.f,0.f,0.f,0.f}};

    const int nk = K >> 6;
    // register prefetch of first k-tile
    short8 ra0 = *(const short8*)(A + (size_t)(m0 + sr) * K + sb * 8);
    short8 ra1 = *(const short8*)(A + (size_t)(m0 + sr + 32) * K + sb * 8);
    short8 rw0 = *(const short8*)(W + (size_t)(n0 + sr) * K + sb * 8);
    short8 rw1 = *(const short8*)(W + (size_t)(n0 + sr + 32) * K + sb * 8);

    for (int kt = 0; kt < nk; ++kt) {
        __syncthreads();
        *(short8*)&la[swz(sr, sb)]      = ra0;
        *(short8*)&la[swz(sr + 32, sb)] = ra1;
        *(short8*)&lw[swz(sr, sb)]      = rw0;
        *(short8*)&lw[swz(sr + 32, sb)] = rw1;
        __syncthreads();
        if (kt + 1 < nk) {
            const int k0 = (kt + 1) * 64;
            ra0 = *(const short8*)(A + (size_t)(m0 + sr) * K + k0 + sb * 8);
            ra1 = *(const short8*)(A + (size_t)(m0 + sr + 32) * K + k0 + sb * 8);
            rw0 = *(const short8*)(W + (size_t)(n0 + sr) * K + k0 + sb * 8);
            rw1 = *(const short8*)(W + (size_t)(n0 + sr + 32) * K + k0 + sb * 8);
        }
        const int arow = wave * 16 + l16;
        short8 a0 = *(const short8*)&la[swz(arow, quad)];
        short8 a1 = *(const short8*)&la[swz(arow, quad + 4)];
        #pragma unroll
        for (int nt = 0; nt < 4; ++nt) {
            const int brow = nt * 16 + l16;
            short8 b0 = *(const short8*)&lw[swz(brow, quad)];
            short8 b1 = *(const short8*)&lw[swz(brow, quad + 4)];
            acc[nt] = __builtin_amdgcn_mfma_f32_16x16x32_bf16(a0, b0, acc[nt], 0, 0, 0);
            acc[nt] = __builtin_amdgcn_mfma_f32_16x16x32_bf16(a1, b1, acc[nt], 0, 0, 0);
        }
    }

    const int mrow = m0 + wave * 16 + quad * 4;
    if (mode == 2) {
        #pragma unroll
        for (int nt = 0; nt < 4; ++nt) {
            int col = n0 + nt * 16 + l16;
            float bv = bias[col];
            #pragma unroll
            for (int r = 0; r < 4; ++r)
                Of[(size_t)(mrow + r) * 640 + ooff + col] = acc[nt][r] + bv;
        }
    } else if (mode == 0 || n0 < C1) {
        #pragma unroll
        for (int nt = 0; nt < 4; ++nt) {
            int col = n0 + nt * 16 + l16;
            #pragma unroll
            for (int r = 0; r < 4; ++r)
                O1[(size_t)(mrow + r) * C1 + col] = __float2bfloat16(acc[nt][r] * oscale);
        }
    } else {
        // V part: write transposed [B,H,64,N]
        #pragma unroll
        for (int nt = 0; nt < 4; ++nt) {
            int col = n0 + nt * 16 + l16 - C1;
            int h = col >> 6, d = col & 63;
            #pragma unroll
            for (int r = 0; r < 4; ++r) {
                int m = mrow + r;
                int b = m >> 12, n = m & (Nn - 1);
                O2[((size_t)(b * Hh + h) * 64 + d) * Nn + n] = __float2bfloat16(acc[nt][r]);
            }
        }
    }
}

// ---------------- flash attention, both branches in one launch ----------------
// Block = 256 q-rows, 4 waves x 64 q-rows (4 q-frags per wave).
// __launch_bounds__(256,3): VGPR <= 170 -> 3 waves/SIMD -> 3 blocks/CU.
// Grid 640 then FULLY co-resident in one round (128 CUs x3 + 128 CUs x2),
// phase-coherent K/V streaming (FETCH ~174 MB; 5 blocks/CU decoheres -> 1.5 GB).
// (r8: VGPR=172 -> 2 waves/SIMD -> 2 blocks/CU + tail round, occupancy 9.7%.)
// K/V/staging/P amortized over 4 q-frags: 6.75 LDS cyc/q-row (vs 10.5 at 2 qf).
// S computed TRANSPOSED: s = mfma(K_frag, Q_frag) -> D[kk][q]; P-store one
// b64/(qf,nt); packed v_cvt_pk bf16 conversion. PV phase holds the 8 V b-frags
// in regs and reads each qf's P-frags just before use (keeps live regs low).
// Q pre-scaled by 0.125*log2(e); fixed m=0 softmax (scores bounded).
__global__ __launch_bounds__(256, 3) void flash_kernel(
    const bf16* __restrict__ Q1, const bf16* __restrict__ K1,
    const bf16* __restrict__ V1, bf16* __restrict__ Y1,
    const bf16* __restrict__ Q2, const bf16* __restrict__ K2,
    const bf16* __restrict__ V2, bf16* __restrict__ Y2)
{
    __shared__ bf16 lk[64 * 64];        // K tile  [k][d], swizzled
    __shared__ bf16 lv[64 * 64];        // V tile  [d][k], swizzled (from pre-transposed Vt)
    __shared__ bf16 lp[4 * 64 * 64];    // per-wave P tile [64 q][64 k], swizzled
    const int qt = blockIdx.x, h = blockIdx.y, z = blockIdx.z;
    const int b = z & 3, branch = z >> 2;
    const bf16* Q  = branch ? Q2 : Q1;
    const bf16* Km = branch ? K2 : K1;
    const bf16* Vt = branch ? V2 : V1;
    bf16*       Y  = branch ? Y2 : Y1;

    const int t = threadIdx.x;
    const int wave = t >> 6, lane = t & 63, l16 = lane & 15, quad = lane >> 4;
    const int sr = t >> 3, sb = t & 7;

    // Q fragments (B-operand): 4 q-frags (64 q-rows) in registers for the whole loop
    short8 aq[4][2];
    #pragma unroll
    for (int qf = 0; qf < 4; ++qf) {
        const bf16* qptr = Q + (size_t)(b * Nn + qt * 256 + wave * 64 + qf * 16 + l16) * C1
                             + h * HD + quad * 8;
        aq[qf][0] = *(const short8*)qptr;
        aq[qf][1] = *(const short8*)(qptr + 32);
    }

    f32x4 acc[4][4];
    float lsum[4] = {0.f, 0.f, 0.f, 0.f};
    #pragma unroll
    for (int qf = 0; qf < 4; ++qf)
        #pragma unroll
        for (int i = 0; i < 4; ++i) acc[qf][i] = {0.f,0.f,0.f,0.f};

    const bf16* Kbase = Km + (size_t)b * Nn * C1 + h * HD;
    const bf16* Vbase = Vt + (size_t)(b * Hh + h) * 64 * Nn;
    const int wbase = wave * (64 * 64);

    // register prefetch of the k-tile staging data
    short8 rk0 = *(const short8*)(Kbase + (size_t)sr * C1 + sb * 8);
    short8 rk1 = *(const short8*)(Kbase + (size_t)(sr + 32) * C1 + sb * 8);
    short8 rv0 = *(const short8*)(Vbase + (size_t)sr * Nn + sb * 8);
    short8 rv1 = *(const short8*)(Vbase + (size_t)(sr + 32) * Nn + sb * 8);

    const int NT = Nn / 64;
    for (int kt = 0; kt < NT; ++kt) {
        __syncthreads();                         // prior iter's readers done
        *(short8*)&lk[swz(sr, sb)]      = rk0;
        *(short8*)&lk[swz(sr + 32, sb)] = rk1;
        *(short8*)&lv[swz(sr, sb)]      = rv0;
        *(short8*)&lv[swz(sr + 32, sb)] = rv1;
        __syncthreads();
        if (kt + 1 < NT) {                       // prefetch next tile; overlaps compute
            const int kn = (kt + 1) * 64;
            rk0 = *(const short8*)(Kbase + (size_t)(kn + sr) * C1 + sb * 8);
            rk1 = *(const short8*)(Kbase + (size_t)(kn + sr + 32) * C1 + sb * 8);
            rv0 = *(const short8*)(Vbase + (size_t)sr * Nn + kn + sb * 8);
            rv1 = *(const short8*)(Vbase + (size_t)(sr + 32) * Nn + kn + sb * 8);
        }

        // S^T = K Q^T for all 4 qf (K frags loaded once per nt); fused exp+pack+store
        #pragma unroll
        for (int nt = 0; nt < 4; ++nt) {
            const int krow = nt * 16 + l16;
            short8 k0 = *(const short8*)&lk[swz(krow, quad)];
            short8 k1 = *(const short8*)&lk[swz(krow, quad + 4)];
            #pragma unroll
            for (int qf = 0; qf < 4; ++qf) {
                f32x4 z4 = {0.f, 0.f, 0.f, 0.f};
                z4 = __builtin_amdgcn_mfma_f32_16x16x32_bf16(k0, aq[qf][0], z4, 0, 0, 0);
                z4 = __builtin_amdgcn_mfma_f32_16x16x32_bf16(k1, aq[qf][1], z4, 0, 0, 0);
                float p0 = fexp2(z4[0]);
                float p1 = fexp2(z4[1]);
                float p2 = fexp2(z4[2]);
                float p3 = fexp2(z4[3]);
                lsum[qf] += (p0 + p1) + (p2 + p3);
                short4_ pk = pack4(p0, p1, p2, p3);
                *(short4_*)&lp[wbase + swz(qf * 16 + l16, nt * 2 + (quad >> 1)) + (quad & 1) * 4] = pk;
            }
        }
        // no barrier: each wave reads back only its own lp region (per-wave DS order)

        // PV phase: hold the 8 V b-frags in regs; per qf read its 2 P a-frags
        // just before use (live ap regs stay at 8 instead of 32).
        short8 bv[4][2];
        #pragma unroll
        for (int dt = 0; dt < 4; ++dt) {
            const int vrow = dt * 16 + l16;
            bv[dt][0] = *(const short8*)&lv[swz(vrow, quad)];
            bv[dt][1] = *(const short8*)&lv[swz(vrow, quad + 4)];
        }
        #pragma unroll
        for (int qf = 0; qf < 4; ++qf) {
            const int prow = qf * 16 + l16;
            short8 ap0 = *(const short8*)&lp[wbase + swz(prow, quad)];
            short8 ap1 = *(const short8*)&lp[wbase + swz(prow, quad + 4)];
            #pragma unroll
            for (int dt = 0; dt < 4; ++dt) {
                acc[qf][dt] = __builtin_amdgcn_mfma_f32_16x16x32_bf16(ap0, bv[dt][0], acc[qf][dt], 0, 0, 0);
                acc[qf][dt] = __builtin_amdgcn_mfma_f32_16x16x32_bf16(ap1, bv[dt][1], acc[qf][dt], 0, 0, 0);
            }
        }
    }

    // epilogue: reduce lsum over quads (q lives on l16), redistribute to acc rows
    #pragma unroll
    for (int qf = 0; qf < 4; ++qf) {
        float l = lsum[qf];
        l += __shfl_xor(l, 16, 64);
        l += __shfl_xor(l, 32, 64);
        #pragma unroll
        for (int reg = 0; reg < 4; ++reg) {
            float lr = __shfl(l, quad * 4 + reg, 64);   // row sum for q = qf*16+quad*4+reg
            float inv = 1.0f / lr;
            size_t rowoff = (size_t)(b * Nn + qt * 256 + wave * 64 + qf * 16 + quad * 4 + reg) * C1
                          + h * HD + l16;
            #pragma unroll
            for (int dt = 0; dt < 4; ++dt)
                Y[rowoff + dt * 16] = __float2bfloat16(acc[qf][dt][reg] * inv);
        }
    }
}

extern "C" void kernel_launch(void* const* d_in, const int* in_sizes, int n_in,
                              void* d_out, int out_size, void* d_ws, size_t ws_size,
                              hipStream_t stream)
{
    const float* x1   = (const float*)d_in[0];
    const float* x2   = (const float*)d_in[1];
    const float* q1w  = (const float*)d_in[2];
    const float* q2w  = (const float*)d_in[3];
    const float* kv1w = (const float*)d_in[4];
    const float* kv2w = (const float*)d_in[5];
    const float* p1w  = (const float*)d_in[6];
    const float* p1b  = (const float*)d_in[7];
    const float* p2w  = (const float*)d_in[8];
    const float* p2b  = (const float*)d_in[9];
    float* out = (float*)d_out;

    bf16* ws = (bf16*)d_ws;
    size_t o = 0;
    bf16* x1b  = ws + o; o += (size_t)Mm * C1;
    bf16* x2b  = ws + o; o += (size_t)Mm * C2;
    bf16* wq1  = ws + o; o += C1 * C1;
    bf16* wq2  = ws + o; o += C1 * C2;
    bf16* wkv1 = ws + o; o += 2 * C1 * C2;
    bf16* wkv2 = ws + o; o += 2 * C1 * C1;
    bf16* wp1  = ws + o; o += C1 * C1;
    bf16* wp2  = ws + o; o += C1 * C1;
    bf16* Q1   = ws + o; o += (size_t)Mm * C1;
    bf16* K1   = ws + o; o += (size_t)Mm * C1;
    bf16* V1t  = ws + o; o += (size_t)Mm * C1;      // [B,H,64,N]
    bf16* Q2   = ws + o; o += (size_t)Mm * C1;
    bf16* K2   = ws + o; o += (size_t)Mm * C1;
    bf16* V2t  = ws + o; o += (size_t)Mm * C1;
    bf16* Y1   = ws + o; o += (size_t)Mm * C1;
    bf16* Y2   = ws + o; o += (size_t)Mm * C1;
    (void)ws_size; (void)in_sizes; (void)n_in; (void)out_size;

    // one convert launch for all 8 fp32->bf16 tensors
    CvtArgs ca;
    ca.s[0] = x1;   ca.d[0] = x1b;  int n0 = Mm * C1;
    ca.s[1] = x2;   ca.d[1] = x2b;  int n1 = Mm * C2;
    ca.s[2] = q1w;  ca.d[2] = wq1;  int n2 = C1 * C1;
    ca.s[3] = q2w;  ca.d[3] = wq2;  int n3 = C1 * C2;
    ca.s[4] = kv1w; ca.d[4] = wkv1; int n4 = 2 * C1 * C2;
    ca.s[5] = kv2w; ca.d[5] = wkv2; int n5 = 2 * C1 * C1;
    ca.s[6] = p1w;  ca.d[6] = wp1;  int n6 = C1 * C1;
    ca.s[7] = p2w;  ca.d[7] = wp2;  int n7 = C1 * C1;
    int ns[8] = {n0, n1, n2, n3, n4, n5, n6, n7};
    ca.off[0] = 0;
    for (int i = 0; i < 8; ++i) ca.off[i + 1] = ca.off[i] + ns[i];
    int total = ca.off[8];
    cvt_all<<<dim3((total / 4 + 255) / 256), 256, 0, stream>>>(ca);

    const float QS = 0.125f * 1.4426950408889634f;   // scale * log2(e), folded into Q

    // Q/KV projections
    gemm_bt<<<dim3(Mm / 64, C1 / 64), 256, 0, stream>>>(x1b, wq1, C1, 0, QS, Q1, nullptr, nullptr, nullptr, 0);
    gemm_bt<<<dim3(Mm / 64, (2 * C1) / 64), 256, 0, stream>>>(x2b, wkv1, C2, 1, 1.0f, K1, V1t, nullptr, nullptr, 0);
    gemm_bt<<<dim3(Mm / 64, C1 / 64), 256, 0, stream>>>(x2b, wq2, C2, 0, QS, Q2, nullptr, nullptr, nullptr, 0);
    gemm_bt<<<dim3(Mm / 64, (2 * C1) / 64), 256, 0, stream>>>(x1b, wkv2, C1, 1, 1.0f, K2, V2t, nullptr, nullptr, 0);

    // attention, both branches in one launch; 256 q-rows per block, grid 640
    flash_kernel<<<dim3(Nn / 256, Hh, 2 * Bb), 256, 0, stream>>>(Q1, K1, V1t, Y1, Q2, K2, V2t, Y2);

    // output projections (fused bias + concat layout)
    gemm_bt<<<dim3(Mm / 64, C1 / 64), 256, 0, stream>>>(Y1, wp1, C1, 2, 1.0f, nullptr, nullptr, p1b, out, 0);
    gemm_bt<<<dim3(Mm / 64, C1 / 64), 256, 0, stream>>>(Y2, wp2, C1, 2, 1.0f, nullptr, nullptr, p2b, out, C1);
}

// Round 10
// 495.118 us; speedup vs baseline: 1.6489x; 1.6489x over previous
//
#include <hip/hip_runtime.h>
#include <hip/hip_bf16.h>

#define Bb 4
#define Nn 4096
#define C1 320
#define C2 256
#define Hh 5
#define HD 64
#define Mm (Bb*Nn)   // 16384

using bf16 = __hip_bfloat16;
typedef __attribute__((ext_vector_type(8))) short  short8;   // 8 bf16 = one MFMA A/B frag
typedef __attribute__((ext_vector_type(4))) short  short4_;
typedef __attribute__((ext_vector_type(4))) float  f32x4;    // MFMA C/D frag

__device__ __forceinline__ short f2s(float f) {
    bf16 h = __float2bfloat16(f);
    short s;
    __builtin_memcpy(&s, &h, 2);
    return s;
}

__device__ __forceinline__ float fexp2(float x) {
#if __has_builtin(__builtin_amdgcn_exp2f)
    return __builtin_amdgcn_exp2f(x);
#else
    return exp2f(x);
#endif
}

// packed f32x2 -> bf16x2 conversion (v_cvt_pk path), 4 values -> short4
__device__ __forceinline__ short4_ pack4(float p0, float p1, float p2, float p3) {
    float2 u; u.x = p0; u.y = p1;
    float2 v; v.x = p2; v.y = p3;
    __hip_bfloat162 a = __float22bfloat162_rn(u);
    __hip_bfloat162 b = __float22bfloat162_rn(v);
    short4_ r;
    __builtin_memcpy(&r, &a, 4);
    short tmp[2];
    __builtin_memcpy(tmp, &b, 4);
    r[2] = tmp[0]; r[3] = tmp[1];
    return r;
}

// XOR-swizzled LDS tile addressing: 64-elem rows, 8 blocks of 8 bf16 (16B).
// physical elem offset of (row, logical block bb) = row*64 + (bb ^ (row&7))*8
__device__ __forceinline__ int swz(int row, int bb) {
    return row * 64 + ((bb ^ (row & 7)) << 3);
}

// async global->LDS DMA, 16 B per lane; LDS fill is wave-uniform-base + lane*16
__device__ __forceinline__ void load_lds16(const bf16* g, bf16* l) {
    __builtin_amdgcn_global_load_lds(
        (const __attribute__((address_space(1))) unsigned int*)g,
        (__attribute__((address_space(3))) unsigned int*)l,
        16, 0, 0);
}

// ---------------- fp32 -> bf16 convert, all 8 tensors in one launch ----------------
struct CvtArgs {
    const float* s[8];
    bf16* d[8];
    int off[9];   // cumulative offsets, off[8] = total
};

__global__ void cvt_all(CvtArgs a) {
    int i = (blockIdx.x * blockDim.x + threadIdx.x) * 4;
    if (i >= a.off[8]) return;
    int seg = 0;
    #pragma unroll
    for (int k = 1; k < 8; ++k) seg += (i >= a.off[k]);
    int j = i - a.off[seg];
    float4 v = *(const float4*)(a.s[seg] + j);
    short4_ o = { f2s(v.x), f2s(v.y), f2s(v.z), f2s(v.w) };
    *(short4_*)(a.d[seg] + j) = o;
}

// ---------------- generic GEMM: C[M,n0..] = A[M,K] x W[Nout,K]^T ----------------
// mode 0: store bf16*oscale to O1[row*320+col]
// mode 1: col<320 -> O1 (K part, [M,320]); col>=320 -> O2 = V transposed [B,H,64,N]
// mode 2: fp32 out Of[row*640 + ooff + col] + bias[col]
__global__ __launch_bounds__(256) void gemm_bt(
    const bf16* __restrict__ A, const bf16* __restrict__ W,
    int K, int mode, float oscale,
    bf16* __restrict__ O1, bf16* __restrict__ O2,
    const float* __restrict__ bias, float* __restrict__ Of, int ooff)
{
    __shared__ bf16 la[64 * 64];
    __shared__ bf16 lw[64 * 64];
    const int m0 = blockIdx.x * 64, n0 = blockIdx.y * 64;
    const int t = threadIdx.x;
    const int wave = t >> 6, lane = t & 63, l16 = lane & 15, quad = lane >> 4;
    const int sr = t >> 3, sb = t & 7;

    f32x4 acc[4] = {{0.f,0.f,0.f,0.f},{0.f,0.f,0.f,0.f},{0.f,0.f,0.f,0.f},{0.f,0.f,0.f,0.f}};

    const int nk = K >> 6;
    // register prefetch of first k-tile
    short8 ra0 = *(const short8*)(A + (size_t)(m0 + sr) * K + sb * 8);
    short8 ra1 = *(const short8*)(A + (size_t)(m0 + sr + 32) * K + sb * 8);
    short8 rw0 = *(const short8*)(W + (size_t)(n0 + sr) * K + sb * 8);
    short8 rw1 = *(const short8*)(W + (size_t)(n0 + sr + 32) * K + sb * 8);

    for (int kt = 0; kt < nk; ++kt) {
        __syncthreads();
        *(short8*)&la[swz(sr, sb)]      = ra0;
        *(short8*)&la[swz(sr + 32, sb)] = ra1;
        *(short8*)&lw[swz(sr, sb)]      = rw0;
        *(short8*)&lw[swz(sr + 32, sb)] = rw1;
        __syncthreads();
        if (kt + 1 < nk) {
            const int k0 = (kt + 1) * 64;
            ra0 = *(const short8*)(A + (size_t)(m0 + sr) * K + k0 + sb * 8);
            ra1 = *(const short8*)(A + (size_t)(m0 + sr + 32) * K + k0 + sb * 8);
            rw0 = *(const short8*)(W + (size_t)(n0 + sr) * K + k0 + sb * 8);
            rw1 = *(const short8*)(W + (size_t)(n0 + sr + 32) * K + k0 + sb * 8);
        }
        const int arow = wave * 16 + l16;
        short8 a0 = *(const short8*)&la[swz(arow, quad)];
        short8 a1 = *(const short8*)&la[swz(arow, quad + 4)];
        #pragma unroll
        for (int nt = 0; nt < 4; ++nt) {
            const int brow = nt * 16 + l16;
            short8 b0 = *(const short8*)&lw[swz(brow, quad)];
            short8 b1 = *(const short8*)&lw[swz(brow, quad + 4)];
            acc[nt] = __builtin_amdgcn_mfma_f32_16x16x32_bf16(a0, b0, acc[nt], 0, 0, 0);
            acc[nt] = __builtin_amdgcn_mfma_f32_16x16x32_bf16(a1, b1, acc[nt], 0, 0, 0);
        }
    }

    const int mrow = m0 + wave * 16 + quad * 4;
    if (mode == 2) {
        #pragma unroll
        for (int nt = 0; nt < 4; ++nt) {
            int col = n0 + nt * 16 + l16;
            float bv = bias[col];
            #pragma unroll
            for (int r = 0; r < 4; ++r)
                Of[(size_t)(mrow + r) * 640 + ooff + col] = acc[nt][r] + bv;
        }
    } else if (mode == 0 || n0 < C1) {
        #pragma unroll
        for (int nt = 0; nt < 4; ++nt) {
            int col = n0 + nt * 16 + l16;
            #pragma unroll
            for (int r = 0; r < 4; ++r)
                O1[(size_t)(mrow + r) * C1 + col] = __float2bfloat16(acc[nt][r] * oscale);
        }
    } else {
        // V part: write transposed [B,H,64,N]
        #pragma unroll
        for (int nt = 0; nt < 4; ++nt) {
            int col = n0 + nt * 16 + l16 - C1;
            int h = col >> 6, d = col & 63;
            #pragma unroll
            for (int r = 0; r < 4; ++r) {
                int m = mrow + r;
                int b = m >> 12, n = m & (Nn - 1);
                O2[((size_t)(b * Hh + h) * 64 + d) * Nn + n] = __float2bfloat16(acc[nt][r]);
            }
        }
    }
}

// ---------------- flash attention, both branches in one launch ----------------
// Block = 256 q-rows, 4 waves x 64 q-rows (4 q-frags per wave). Grid 640.
// K/V staging via __builtin_amdgcn_global_load_lds width=16 (m97 pattern):
// no staging VGPRs -> live regs ~145, fits 3 waves/SIMD WITHOUT spills
// (r9: reg-prefetch pushed it to 172; launch_bounds(256,3) then spilled
// 848 MB of scratch). LDS swizzle preserved by swizzling the GLOBAL source
// column per lane (lane reads block (i&7)^(row&7), DMA lands lane-linear).
// LDS kept at 48 KB DELIBERATELY -> 3 blocks/CU -> 768 capacity >= 640 grid:
// single co-resident round, below the 5-blocks/CU stream-decoherence
// threshold (r6/r7: FETCH exploded to 1.5 GB).
// S computed TRANSPOSED: s = mfma(K_frag, Q_frag) -> D[kk][q]; P-store one
// b64/(qf,nt); packed v_cvt_pk bf16. PV holds 8 V b-frags, reads P per qf.
// Q pre-scaled by 0.125*log2(e); fixed m=0 softmax (scores bounded).
__global__ __launch_bounds__(256, 3) void flash_kernel(
    const bf16* __restrict__ Q1, const bf16* __restrict__ K1,
    const bf16* __restrict__ V1, bf16* __restrict__ Y1,
    const bf16* __restrict__ Q2, const bf16* __restrict__ K2,
    const bf16* __restrict__ V2, bf16* __restrict__ Y2)
{
    __shared__ bf16 lk[64 * 64];        // K tile  [k][d], swizzled
    __shared__ bf16 lv[64 * 64];        // V tile  [d][k], swizzled (from pre-transposed Vt)
    __shared__ bf16 lp[4 * 64 * 64];    // per-wave P tile [64 q][64 k], swizzled
    const int qt = blockIdx.x, h = blockIdx.y, z = blockIdx.z;
    const int b = z & 3, branch = z >> 2;
    const bf16* Q  = branch ? Q2 : Q1;
    const bf16* Km = branch ? K2 : K1;
    const bf16* Vt = branch ? V2 : V1;
    bf16*       Y  = branch ? Y2 : Y1;

    const int t = threadIdx.x;
    const int wave = t >> 6, lane = t & 63, l16 = lane & 15, quad = lane >> 4;

    // Q fragments (B-operand): 4 q-frags (64 q-rows) in registers for the whole loop
    short8 aq[4][2];
    #pragma unroll
    for (int qf = 0; qf < 4; ++qf) {
        const bf16* qptr = Q + (size_t)(b * Nn + qt * 256 + wave * 64 + qf * 16 + l16) * C1
                             + h * HD + quad * 8;
        aq[qf][0] = *(const short8*)qptr;
        aq[qf][1] = *(const short8*)(qptr + 32);
    }

    f32x4 acc[4][4];
    float lsum[4] = {0.f, 0.f, 0.f, 0.f};
    #pragma unroll
    for (int qf = 0; qf < 4; ++qf)
        #pragma unroll
        for (int i = 0; i < 4; ++i) acc[qf][i] = {0.f,0.f,0.f,0.f};

    const bf16* Kbase = Km + (size_t)b * Nn * C1 + h * HD;
    const bf16* Vbase = Vt + (size_t)(b * Hh + h) * 64 * Nn;
    const int wbase = wave * (64 * 64);

    // DMA staging addressing: wave w fills rows w*16..w*16+15 of lk and lv,
    // two instrs each (8 rows per instr). Source column-block is XOR-swizzled
    // so the lane-linear LDS fill lands in swz() layout.
    const int rowA = wave * 16 + (lane >> 3);        // rows w*16..+7
    const int rowB = rowA + 8;                       // rows w*16+8..+15
    const int cbA = (lane & 7) ^ (rowA & 7);
    const int cbB = (lane & 7) ^ (rowB & 7);
    const bf16* kgA = Kbase + (size_t)rowA * C1 + cbA * 8;
    const bf16* kgB = Kbase + (size_t)rowB * C1 + cbB * 8;
    const bf16* vgA = Vbase + (size_t)rowA * Nn + cbA * 8;
    const bf16* vgB = Vbase + (size_t)rowB * Nn + cbB * 8;
    bf16* lkA = &lk[(wave * 16) * 64];
    bf16* lkB = &lk[(wave * 16 + 8) * 64];
    bf16* lvA = &lv[(wave * 16) * 64];
    bf16* lvB = &lv[(wave * 16 + 8) * 64];

    const int NT = Nn / 64;
    for (int kt = 0; kt < NT; ++kt) {
        __syncthreads();                 // prior iter's frag reads done
        load_lds16(kgA, lkA);
        load_lds16(kgB, lkB);
        load_lds16(vgA, lvA);
        load_lds16(vgB, lvB);
        __syncthreads();                 // vmcnt(0) drain: DMA complete
        kgA += 64 * C1; kgB += 64 * C1;
        vgA += 64;      vgB += 64;

        // S^T = K Q^T for all 4 qf (K frags loaded once per nt); fused exp+pack+store
        #pragma unroll
        for (int nt = 0; nt < 4; ++nt) {
            const int krow = nt * 16 + l16;
            short8 k0 = *(const short8*)&lk[swz(krow, quad)];
            short8 k1 = *(const short8*)&lk[swz(krow, quad + 4)];
            #pragma unroll
            for (int qf = 0; qf < 4; ++qf) {
                f32x4 z4 = {0.f, 0.f, 0.f, 0.f};
                z4 = __builtin_amdgcn_mfma_f32_16x16x32_bf16(k0, aq[qf][0], z4, 0, 0, 0);
                z4 = __builtin_amdgcn_mfma_f32_16x16x32_bf16(k1, aq[qf][1], z4, 0, 0, 0);
                float p0 = fexp2(z4[0]);
                float p1 = fexp2(z4[1]);
                float p2 = fexp2(z4[2]);
                float p3 = fexp2(z4[3]);
                lsum[qf] += (p0 + p1) + (p2 + p3);
                short4_ pk = pack4(p0, p1, p2, p3);
                *(short4_*)&lp[wbase + swz(qf * 16 + l16, nt * 2 + (quad >> 1)) + (quad & 1) * 4] = pk;
            }
        }
        // no barrier: each wave reads back only its own lp region (per-wave DS order)

        // PV phase: hold the 8 V b-frags in regs; per qf read its 2 P a-frags
        // just before use (keeps live regs low).
        short8 bv[4][2];
        #pragma unroll
        for (int dt = 0; dt < 4; ++dt) {
            const int vrow = dt * 16 + l16;
            bv[dt][0] = *(const short8*)&lv[swz(vrow, quad)];
            bv[dt][1] = *(const short8*)&lv[swz(vrow, quad + 4)];
        }
        #pragma unroll
        for (int qf = 0; qf < 4; ++qf) {
            const int prow = qf * 16 + l16;
            short8 ap0 = *(const short8*)&lp[wbase + swz(prow, quad)];
            short8 ap1 = *(const short8*)&lp[wbase + swz(prow, quad + 4)];
            #pragma unroll
            for (int dt = 0; dt < 4; ++dt) {
                acc[qf][dt] = __builtin_amdgcn_mfma_f32_16x16x32_bf16(ap0, bv[dt][0], acc[qf][dt], 0, 0, 0);
                acc[qf][dt] = __builtin_amdgcn_mfma_f32_16x16x32_bf16(ap1, bv[dt][1], acc[qf][dt], 0, 0, 0);
            }
        }
    }

    // epilogue: reduce lsum over quads (q lives on l16), redistribute to acc rows
    #pragma unroll
    for (int qf = 0; qf < 4; ++qf) {
        float l = lsum[qf];
        l += __shfl_xor(l, 16, 64);
        l += __shfl_xor(l, 32, 64);
        #pragma unroll
        for (int reg = 0; reg < 4; ++reg) {
            float lr = __shfl(l, quad * 4 + reg, 64);   // row sum for q = qf*16+quad*4+reg
            float inv = 1.0f / lr;
            size_t rowoff = (size_t)(b * Nn + qt * 256 + wave * 64 + qf * 16 + quad * 4 + reg) * C1
                          + h * HD + l16;
            #pragma unroll
            for (int dt = 0; dt < 4; ++dt)
                Y[rowoff + dt * 16] = __float2bfloat16(acc[qf][dt][reg] * inv);
        }
    }
}

extern "C" void kernel_launch(void* const* d_in, const int* in_sizes, int n_in,
                              void* d_out, int out_size, void* d_ws, size_t ws_size,
                              hipStream_t stream)
{
    const float* x1   = (const float*)d_in[0];
    const float* x2   = (const float*)d_in[1];
    const float* q1w  = (const float*)d_in[2];
    const float* q2w  = (const float*)d_in[3];
    const float* kv1w = (const float*)d_in[4];
    const float* kv2w = (const float*)d_in[5];
    const float* p1w  = (const float*)d_in[6];
    const float* p1b  = (const float*)d_in[7];
    const float* p2w  = (const float*)d_in[8];
    const float* p2b  = (const float*)d_in[9];
    float* out = (float*)d_out;

    bf16* ws = (bf16*)d_ws;
    size_t o = 0;
    bf16* x1b  = ws + o; o += (size_t)Mm * C1;
    bf16* x2b  = ws + o; o += (size_t)Mm * C2;
    bf16* wq1  = ws + o; o += C1 * C1;
    bf16* wq2  = ws + o; o += C1 * C2;
    bf16* wkv1 = ws + o; o += 2 * C1 * C2;
    bf16* wkv2 = ws + o; o += 2 * C1 * C1;
    bf16* wp1  = ws + o; o += C1 * C1;
    bf16* wp2  = ws + o; o += C1 * C1;
    bf16* Q1   = ws + o; o += (size_t)Mm * C1;
    bf16* K1   = ws + o; o += (size_t)Mm * C1;
    bf16* V1t  = ws + o; o += (size_t)Mm * C1;      // [B,H,64,N]
    bf16* Q2   = ws + o; o += (size_t)Mm * C1;
    bf16* K2   = ws + o; o += (size_t)Mm * C1;
    bf16* V2t  = ws + o; o += (size_t)Mm * C1;
    bf16* Y1   = ws + o; o += (size_t)Mm * C1;
    bf16* Y2   = ws + o; o += (size_t)Mm * C1;
    (void)ws_size; (void)in_sizes; (void)n_in; (void)out_size;

    // one convert launch for all 8 fp32->bf16 tensors
    CvtArgs ca;
    ca.s[0] = x1;   ca.d[0] = x1b;  int n0 = Mm * C1;
    ca.s[1] = x2;   ca.d[1] = x2b;  int n1 = Mm * C2;
    ca.s[2] = q1w;  ca.d[2] = wq1;  int n2 = C1 * C1;
    ca.s[3] = q2w;  ca.d[3] = wq2;  int n3 = C1 * C2;
    ca.s[4] = kv1w; ca.d[4] = wkv1; int n4 = 2 * C1 * C2;
    ca.s[5] = kv2w; ca.d[5] = wkv2; int n5 = 2 * C1 * C1;
    ca.s[6] = p1w;  ca.d[6] = wp1;  int n6 = C1 * C1;
    ca.s[7] = p2w;  ca.d[7] = wp2;  int n7 = C1 * C1;
    int ns[8] = {n0, n1, n2, n3, n4, n5, n6, n7};
    ca.off[0] = 0;
    for (int i = 0; i < 8; ++i) ca.off[i + 1] = ca.off[i] + ns[i];
    int total = ca.off[8];
    cvt_all<<<dim3((total / 4 + 255) / 256), 256, 0, stream>>>(ca);

    const float QS = 0.125f * 1.4426950408889634f;   // scale * log2(e), folded into Q

    // Q/KV projections
    gemm_bt<<<dim3(Mm / 64, C1 / 64), 256, 0, stream>>>(x1b, wq1, C1, 0, QS, Q1, nullptr, nullptr, nullptr, 0);
    gemm_bt<<<dim3(Mm / 64, (2 * C1) / 64), 256, 0, stream>>>(x2b, wkv1, C2, 1, 1.0f, K1, V1t, nullptr, nullptr, 0);
    gemm_bt<<<dim3(Mm / 64, C1 / 64), 256, 0, stream>>>(x2b, wq2, C2, 0, QS, Q2, nullptr, nullptr, nullptr, 0);
    gemm_bt<<<dim3(Mm / 64, (2 * C1) / 64), 256, 0, stream>>>(x1b, wkv2, C1, 1, 1.0f, K2, V2t, nullptr, nullptr, 0);

    // attention, both branches in one launch; 256 q-rows per block, grid 640
    flash_kernel<<<dim3(Nn / 256, Hh, 2 * Bb), 256, 0, stream>>>(Q1, K1, V1t, Y1, Q2, K2, V2t, Y2);

    // output projections (fused bias + concat layout)
    gemm_bt<<<dim3(Mm / 64, C1 / 64), 256, 0, stream>>>(Y1, wp1, C1, 2, 1.0f, nullptr, nullptr, p1b, out, 0);
    gemm_bt<<<dim3(Mm / 64, C1 / 64), 256, 0, stream>>>(Y2, wp2, C1, 2, 1.0f, nullptr, nullptr, p2b, out, C1);
}